// Round 14
// baseline (551.665 us; speedup 1.0000x reference)
//
#include <hip/hip_runtime.h>
#include <stdint.h>

#define M_DIM 8192
#define K_DIM 4096
#define N_DIM 4096

using f32x4 = __attribute__((ext_vector_type(4))) float;
using i32x4 = __attribute__((ext_vector_type(4))) int;
using i32x8 = __attribute__((ext_vector_type(8))) int;

#define UNIT_SCALE 0x7F7F7F7F   // 4x E8M0 exponent-127 bytes -> 2^0

// ---------- fp8 e4m3 packing (HW RNE conversion; inputs pre-clipped to +-448) ----------
__device__ inline uint32_t pk_fp8_x4(float a, float b, float c, float d) {
    int lo   = __builtin_amdgcn_cvt_pk_fp8_f32(a, b, 0, false);   // bytes 0,1
    int both = __builtin_amdgcn_cvt_pk_fp8_f32(c, d, lo, true);   // bytes 2,3
    return (uint32_t)both;
}

__device__ inline float clip448(float v) {
    return fminf(fmaxf(v, -448.0f), 448.0f);
}

__device__ inline void gload_lds16(const void* g, void* l) {
    __builtin_amdgcn_global_load_lds(
        (const __attribute__((address_space(1))) uint32_t*)g,
        (__attribute__((address_space(3))) uint32_t*)l, 16, 0, 0);
}

// K-permutation within each 128-byte K-block (for 16x16x128 scaled MFMA):
// orig k (c = k>>5, g = (k>>3)&3, j = k&7)  ->  stored p = g*32 + c*8 + j
// => a GEMM lane (g = lane>>4) reads its 32-byte fragment as logical units 2g, 2g+1.

// ---------- quantize x: f32 [M][K] -> e4m3 [M][K] (K-permuted), per-block amax ----------
__global__ void quant_x_kernel(const float* __restrict__ x, uint8_t* __restrict__ qx,
                               const float* __restrict__ scale_p, float* __restrict__ bm,
                               int n8) {
    __shared__ float red[4];
    const float inv = 1.0f / scale_p[0];
    float lmax = 0.0f;
    const float4* xv = (const float4*)x;
    const int stride = gridDim.x * blockDim.x;
    for (int u = blockIdx.x * blockDim.x + threadIdx.x; u < n8; u += stride) {
        float4 v0 = xv[2 * u];
        float4 v1 = xv[2 * u + 1];
        lmax = fmaxf(lmax, fmaxf(fmaxf(fabsf(v0.x), fabsf(v0.y)),
                                 fmaxf(fabsf(v0.z), fabsf(v0.w))));
        lmax = fmaxf(lmax, fmaxf(fmaxf(fabsf(v1.x), fabsf(v1.y)),
                                 fmaxf(fabsf(v1.z), fabsf(v1.w))));
        uint32_t w0 = pk_fp8_x4(clip448(v0.x * inv), clip448(v0.y * inv),
                                clip448(v0.z * inv), clip448(v0.w * inv));
        uint32_t w1 = pk_fp8_x4(clip448(v1.x * inv), clip448(v1.y * inv),
                                clip448(v1.z * inv), clip448(v1.w * inv));
        // permuted 8B destination within 128B block
        size_t b  = (size_t)(u >> 4);   // 128-byte block
        int   u8  = u & 15;             // orig 8B unit = c*4 + g
        int   c   = u8 >> 2, g = u8 & 3;
        uint2* dst = (uint2*)(qx + b * 128 + (size_t)(g * 4 + c) * 8);
        *dst = make_uint2(w0, w1);
    }
    #pragma unroll
    for (int off = 32; off; off >>= 1) lmax = fmaxf(lmax, __shfl_xor(lmax, off));
    if ((threadIdx.x & 63) == 0) red[threadIdx.x >> 6] = lmax;
    __syncthreads();
    if (threadIdx.x == 0)
        bm[blockIdx.x] = fmaxf(fmaxf(red[0], red[1]), fmaxf(red[2], red[3]));
}

// ---------- quantize kernel transposed: f32 [K][N] -> e4m3 [N][K] (K-permuted) ----------
__global__ void quant_kT_kernel(const float* __restrict__ kin, uint8_t* __restrict__ qkT,
                                const float* __restrict__ scale_p, float* __restrict__ bm) {
    __shared__ uint8_t sm[64 * 68];  // [k 0..63][n 0..63], pad 68
    __shared__ float red[4];
    const float inv = 1.0f / scale_p[0];
    const int t = threadIdx.x;
    const int bk = blockIdx.x & 63;   // K-tile index (64 tiles)
    const int bn = blockIdx.x >> 6;   // N-tile index (64 tiles)
    const int gk0 = bk * 64, gn0 = bn * 64;
    float lmax = 0.0f;

    #pragma unroll
    for (int it = 0; it < 4; ++it) {
        int k  = it * 16 + (t >> 4);
        int n4 = (t & 15) * 4;
        float4 v = *(const float4*)(kin + (size_t)(gk0 + k) * N_DIM + gn0 + n4);
        lmax = fmaxf(lmax, fmaxf(fmaxf(fabsf(v.x), fabsf(v.y)),
                                 fmaxf(fabsf(v.z), fabsf(v.w))));
        *(uint32_t*)(sm + k * 68 + n4) = pk_fp8_x4(clip448(v.x * inv), clip448(v.y * inv),
                                                   clip448(v.z * inv), clip448(v.w * inv));
    }
    __syncthreads();
    #pragma unroll
    for (int it = 0; it < 4; ++it) {
        int n  = it * 16 + (t >> 4);
        int k4 = (t & 15) * 4;                  // 0..60, multiple of 4
        uint32_t w = (uint32_t)sm[(k4 + 0) * 68 + n]
                   | ((uint32_t)sm[(k4 + 1) * 68 + n] << 8)
                   | ((uint32_t)sm[(k4 + 2) * 68 + n] << 16)
                   | ((uint32_t)sm[(k4 + 3) * 68 + n] << 24);
        int kk = (gk0 + k4);
        size_t b = (size_t)(kk >> 7);           // 128-byte block
        int  kp  = kk & 127;
        int  c   = kp >> 5, g = (kp >> 3) & 3, j = kp & 7;   // j in {0,4}
        int  p   = g * 32 + c * 8 + j;
        *(uint32_t*)(qkT + (size_t)(gn0 + n) * K_DIM + b * 128 + p) = w;
    }
    #pragma unroll
    for (int off = 32; off; off >>= 1) lmax = fmaxf(lmax, __shfl_xor(lmax, off));
    if ((t & 63) == 0) red[t >> 6] = lmax;
    __syncthreads();
    if (t == 0)
        bm[blockIdx.x] = fmaxf(fmaxf(red[0], red[1]), fmaxf(red[2], red[3]));
}

// ---------- MX-fp8 GEMM, 256x256 tile, 8-phase, 4 WAVES x (128x128 per wave) ----------
// Port-traffic reduction: per-wave LDS read bytes scale with (Mw+Nw). 4 waves
// of 128x128 = 4x(128+128) = 128 b128/CU/K-tile vs r11's 8x(128+64) = 192
// (-33%). MFMA cycles/CU invariant. r11 counters showed wall = port + MFMA
// exactly serialized, so cutting port traffic cuts wall directly.
// acc = 8x8 f32x4 = 256 VGPR -> 1 wave/SIMD (acceptable: r13 proved TLP
// doesn't help this structure). Schedule/rotation/swizzle identical to r11;
// staging is 4 gload_lds per thread per half-unit (256 threads), so vmcnt
// counts double to 8.

__device__ __forceinline__ i32x8 load_frag(const uint8_t* base, int off) {
    i32x4 lo = *(const i32x4*)(base + off);
    i32x4 hi = *(const i32x4*)(base + (off ^ 16));
    return __builtin_shufflevector(lo, hi, 0, 1, 2, 3, 4, 5, 6, 7);
}

#define SB __builtin_amdgcn_sched_barrier(0)
#define WAITL(N) do { asm volatile("s_waitcnt lgkmcnt(" #N ")" ::: "memory"); \
                      __builtin_amdgcn_sched_barrier(0); } while (0)
#define MM1(qq, nn, areg, breg)                                                 \
    acc[qq][nn] = __builtin_amdgcn_mfma_scale_f32_16x16x128_f8f6f4(             \
        areg, breg, acc[qq][nn], 0, 0, 0, UNIT_SCALE, 0, UNIT_SCALE)
#define MMROW(qq, areg)                                                         \
    do { MM1(qq, 0, areg, bf0); MM1(qq, 1, areg, bf1);                          \
         MM1(qq, 2, areg, bf2); MM1(qq, 3, areg, bf3);                          \
         MM1(qq, 4, areg, bf4); MM1(qq, 5, areg, bf5);                          \
         MM1(qq, 6, areg, bf6); MM1(qq, 7, areg, bf7); } while (0)

__global__ __launch_bounds__(256, 1) void gemm_mx8(
        const uint8_t* __restrict__ A,   // [M][K] e4m3, K-permuted per 128B block
        const uint8_t* __restrict__ Bt,  // [N][K] e4m3, K-permuted per 128B block
        const float* __restrict__ bias,
        const float* __restrict__ sIn, const float* __restrict__ sK,
        float* __restrict__ C) {
    __shared__ uint8_t smA[2][2][16384];
    __shared__ uint8_t smB[2][2][16384];

    const int tid = threadIdx.x;
    const int lane = tid & 63, wid = tid >> 6;     // 4 waves
    const int wm = wid >> 1, wn = wid & 1;         // 2 x 2 wave grid
    const int r = lane & 15, g = lane >> 4;

    // XCD-bijective swizzle: 512 blocks, 512 % 8 == 0
    const int swz = (blockIdx.x & 7) * 64 + (blockIdx.x >> 3);
    const int mt = swz >> 4, nt = swz & 15;           // 32 x 16 tiles
    const int gRow0 = mt * 256, gCol0 = nt * 256;

    // staging geometry: idx = c*256 + tid (0..1023); linear LDS dest idx*16.
    // row = idx>>3 (0..127), phys unit pu = idx&7 holds logical lu = pu ^ (row&7)
    size_t soff[4];
    int    sdst[4];
    #pragma unroll
    for (int c = 0; c < 4; ++c) {
        int idx = c * 256 + tid;
        int row = idx >> 3;
        soff[c] = (size_t)row * K_DIM + (((idx & 7) ^ (row & 7)) * 16);
        sdst[c] = idx * 16;
    }

    const uint8_t* Abase = A  + (size_t)gRow0 * K_DIM;
    const uint8_t* Bbase = Bt + (size_t)gCol0 * K_DIM;

#define STAGE_A(d, h, kt) do {                                                   \
    const uint8_t* s_ = Abase + (size_t)(h) * (128 * (size_t)K_DIM)              \
                              + (size_t)(kt) * 128;                              \
    gload_lds16(s_ + soff[0], &smA[d][h][sdst[0]]);                              \
    gload_lds16(s_ + soff[1], &smA[d][h][sdst[1]]);                              \
    gload_lds16(s_ + soff[2], &smA[d][h][sdst[2]]);                              \
    gload_lds16(s_ + soff[3], &smA[d][h][sdst[3]]); } while (0)
#define STAGE_B(d, h, kt) do {                                                   \
    const uint8_t* s_ = Bbase + (size_t)(h) * (128 * (size_t)K_DIM)              \
                              + (size_t)(kt) * 128;                              \
    gload_lds16(s_ + soff[0], &smB[d][h][sdst[0]]);                              \
    gload_lds16(s_ + soff[1], &smB[d][h][sdst[1]]);                              \
    gload_lds16(s_ + soff[2], &smB[d][h][sdst[2]]);                              \
    gload_lds16(s_ + soff[3], &smB[d][h][sdst[3]]); } while (0)

    f32x4 acc[8][8] = {};

    const int aHalf = wm;
    const int bHalf = wn;

    // precomputed within-operand byte offsets (lo unit) for all 16 fragments
    int aoff[8], boff[8];
    #pragma unroll
    for (int m = 0; m < 8; ++m) {
        int lrow = m * 16 + r;
        int sw   = (((2 * g) ^ (lrow & 7)) * 16);
        aoff[m] = aHalf * 16384 + lrow * 128 + sw;
        boff[m] = bHalf * 16384 + lrow * 128 + sw;
    }
    const uint8_t* smAb = &smA[0][0][0];
    const uint8_t* smBb = &smB[0][0][0];

    // prologue: B-K0, A-K0, B-K1 (6 half-units, 24 loads); keep B-K1 in flight
    STAGE_B(0, 0, 0); STAGE_B(0, 1, 0);
    STAGE_A(0, 0, 0); STAGE_A(0, 1, 0);
    STAGE_B(1, 0, 1); STAGE_B(1, 1, 1);
    asm volatile("s_waitcnt vmcnt(8)" ::: "memory");
    __builtin_amdgcn_s_barrier();                 // cross-wave visibility of kt0

    i32x8 bf0, bf1, bf2, bf3, bf4, bf5, bf6, bf7;

#define PHASE(D, Q, STAGE, VM) do {                                              \
    const uint8_t* As_ = smAb + (D) * 32768;                                     \
    const uint8_t* Bs_ = smBb + (D) * 32768;                                     \
    i32x8 a0, a1;                                                                \
    if ((Q) == 0) {                                                              \
        a0  = load_frag(As_, aoff[0]); SB;                                       \
        a1  = load_frag(As_, aoff[1]); SB;                                       \
        bf0 = load_frag(Bs_, boff[0]); SB;                                       \
        bf1 = load_frag(Bs_, boff[1]); SB;                                       \
        bf2 = load_frag(Bs_, boff[2]); SB;                                       \
        bf3 = load_frag(Bs_, boff[3]); SB;                                       \
        bf4 = load_frag(Bs_, boff[4]); SB;                                       \
        bf5 = load_frag(Bs_, boff[5]); SB;                                       \
        bf6 = load_frag(Bs_, boff[6]); SB;                                       \
        bf7 = load_frag(Bs_, boff[7]); SB;                                       \
    } else {                                                                     \
        a0 = load_frag(As_, aoff[2 * (Q) + 0]); SB;                              \
        a1 = load_frag(As_, aoff[2 * (Q) + 1]); SB;                              \
    }                                                                            \
    STAGE;                                                                       \
    __builtin_amdgcn_s_barrier();                                                \
    __builtin_amdgcn_s_setprio(1);                                               \
    if ((Q) == 0) {                                                              \
        WAITL(14); MM1(0, 0, a0, bf0);                                           \
        WAITL(12); MM1(0, 1, a0, bf1);                                           \
        WAITL(10); MM1(0, 2, a0, bf2);                                           \
        WAITL(8);  MM1(0, 3, a0, bf3);                                           \
        WAITL(6);  MM1(0, 4, a0, bf4);                                           \
        WAITL(4);  MM1(0, 5, a0, bf5);                                           \
        WAITL(2);  MM1(0, 6, a0, bf6);                                           \
        WAITL(0);  MM1(0, 7, a0, bf7);                                           \
        MMROW(1, a1);                                                            \
    } else {                                                                     \
        WAITL(2); MMROW(2 * (Q) + 0, a0);                                        \
        WAITL(0); MMROW(2 * (Q) + 1, a1);                                        \
    }                                                                            \
    __builtin_amdgcn_s_setprio(0);                                               \
    if (VM) asm volatile("s_waitcnt vmcnt(8)" ::: "memory");                     \
    __builtin_amdgcn_s_barrier();                                                \
} while (0)

    for (int i = 0; i < K_DIM / 256; ++i) {          // 16 iterations, 2 K-tiles each
        const int kt1  = 2 * i + 1;
        const int ktn0 = (2 * i + 2) & 31;           // wraps harmlessly on last iter
        const int ktn1 = (2 * i + 3) & 31;
        PHASE(0, 0, STAGE_A(1, 0, kt1),  0);
        PHASE(0, 1, STAGE_A(1, 1, kt1),  0);
        PHASE(0, 2, STAGE_B(0, 0, ktn0), 0);
        PHASE(0, 3, STAGE_B(0, 1, ktn0), 1);
        PHASE(1, 0, STAGE_A(0, 0, ktn0), 0);
        PHASE(1, 1, STAGE_A(0, 1, ktn0), 0);
        PHASE(1, 2, STAGE_B(1, 0, ktn1), 0);
        PHASE(1, 3, STAGE_B(1, 1, ktn1), 1);
    }

    const float s = sIn[0] * sK[0];
    #pragma unroll
    for (int n = 0; n < 8; ++n) {
        const int col = gCol0 + wn * 128 + n * 16 + r;
        const float bv = bias[col];
        #pragma unroll
        for (int m = 0; m < 8; ++m) {
            const int rw = gRow0 + wm * 128 + m * 16 + g * 4;
            #pragma unroll
            for (int reg = 0; reg < 4; ++reg)
                C[(size_t)(rw + reg) * N_DIM + col] = acc[m][n][reg] * s + bv;
        }
    }
#undef PHASE
#undef STAGE_A
#undef STAGE_B
}

// ---------- reduce block maxes + rolling-amax state update ----------
__global__ void state_kernel(const float* __restrict__ bmx, int nx,
                             const float* __restrict__ bmk, int nk,
                             const float* __restrict__ inHist,
                             const float* __restrict__ kHist,
                             float* __restrict__ tail) {
    __shared__ float red[8];
    const int t = threadIdx.x;
    float mx = 0.0f, mk = 0.0f;
    for (int i = t; i < nx; i += 256) mx = fmaxf(mx, bmx[i]);
    for (int i = t; i < nk; i += 256) mk = fmaxf(mk, bmk[i]);
    #pragma unroll
    for (int off = 32; off; off >>= 1) {
        mx = fmaxf(mx, __shfl_xor(mx, off));
        mk = fmaxf(mk, __shfl_xor(mk, off));
    }
    if ((t & 63) == 0) { red[t >> 6] = mx; red[4 + (t >> 6)] = mk; }
    __syncthreads();
    if (t == 0) {
        float amax_x = fmaxf(fmaxf(red[0], red[1]), fmaxf(red[2], red[3]));
        float amax_k = fmaxf(fmaxf(red[4], red[5]), fmaxf(red[6], red[7]));
        #pragma unroll
        for (int which = 0; which < 2; ++which) {
            const float* h = which ? kHist : inHist;
            float ac = which ? amax_k : amax_x;
            float m = fmaxf(0.0009765625f, ac);   // 2^-10
            tail[2 + which * 16 + 0] = ac;
            for (int i = 1; i < 16; ++i) {
                float v = h[i - 1];
                tail[2 + which * 16 + i] = v;
                m = fmaxf(m, v);
            }
            tail[which] = 1.1f * m / 448.0f;
        }
    }
}

extern "C" void kernel_launch(void* const* d_in, const int* in_sizes, int n_in,
                              void* d_out, int out_size, void* d_ws, size_t ws_size,
                              hipStream_t stream) {
    const float* x        = (const float*)d_in[0];
    const float* kern     = (const float*)d_in[1];
    const float* bias     = (const float*)d_in[2];
    const float* in_scale = (const float*)d_in[3];
    const float* k_scale  = (const float*)d_in[4];
    const float* in_hist  = (const float*)d_in[7];
    const float* k_hist   = (const float*)d_in[8];

    const int NBX = 2048;              // quant_x blocks
    const int NBK = 64 * 64;           // quant_kT blocks
    const size_t qx_bytes  = (size_t)M_DIM * K_DIM;       // 32 MiB
    const size_t qkT_bytes = (size_t)K_DIM * N_DIM;       // 16 MiB
    const size_t need = qx_bytes + qkT_bytes + (NBX + NBK) * sizeof(float);
    if (ws_size < need) return;  // fail visibly, no corruption

    uint8_t* qx  = (uint8_t*)d_ws;
    uint8_t* qkT = qx + qx_bytes;
    float*   bmx = (float*)(qkT + qkT_bytes);
    float*   bmk = bmx + NBX;
    float*   out = (float*)d_out;

    quant_x_kernel<<<NBX, 256, 0, stream>>>(x, qx, in_scale, bmx,
                                            (int)((size_t)M_DIM * K_DIM / 8));
    quant_kT_kernel<<<NBK, 256, 0, stream>>>(kern, qkT, k_scale, bmk);
    gemm_mx8<<<(M_DIM / 256) * (N_DIM / 256), 256, 0, stream>>>(qx, qkT, bias,
                                                                in_scale, k_scale, out);
    state_kernel<<<1, 256, 0, stream>>>(bmx, NBX, bmk, NBK, in_hist, k_hist,
                                        out + (size_t)M_DIM * N_DIM);
}

// Round 15
// 197.686 us; speedup vs baseline: 2.7906x; 2.7906x over previous
//
#include <hip/hip_runtime.h>
#include <stdint.h>

#define M_DIM 8192
#define K_DIM 4096
#define N_DIM 4096

using f32x4 = __attribute__((ext_vector_type(4))) float;
using i32x4 = __attribute__((ext_vector_type(4))) int;
using i32x8 = __attribute__((ext_vector_type(8))) int;

#define UNIT_SCALE 0x7F7F7F7F   // 4x E8M0 exponent-127 bytes -> 2^0

// ---------- fp8 e4m3 packing (HW RNE conversion; inputs pre-clipped to +-448) ----------
__device__ inline uint32_t pk_fp8_x4(float a, float b, float c, float d) {
    int lo   = __builtin_amdgcn_cvt_pk_fp8_f32(a, b, 0, false);   // bytes 0,1
    int both = __builtin_amdgcn_cvt_pk_fp8_f32(c, d, lo, true);   // bytes 2,3
    return (uint32_t)both;
}

__device__ inline float clip448(float v) {
    return fminf(fmaxf(v, -448.0f), 448.0f);
}

__device__ inline void gload_lds16(const void* g, void* l) {
    __builtin_amdgcn_global_load_lds(
        (const __attribute__((address_space(1))) uint32_t*)g,
        (__attribute__((address_space(3))) uint32_t*)l, 16, 0, 0);
}

// K-permutation within each 128-byte K-block (for 16x16x128 scaled MFMA):
// orig k (c = k>>5, g = (k>>3)&3, j = k&7)  ->  stored p = g*32 + c*8 + j
// => a GEMM lane (g = lane>>4) reads its 32-byte fragment as logical units 2g, 2g+1.

// ---------- FUSED quantize: blocks [0,4096) do kernel^T, [4096,6144) do x ----------
// (one launch instead of two: removes a launch boundary; both are HBM-bound
// 256-thread kernels, so they tile the CUs together.)
__global__ void quant_fused(const float* __restrict__ x, uint8_t* __restrict__ qx,
                            const float* __restrict__ xs_p, float* __restrict__ bmx, int n8,
                            const float* __restrict__ kin, uint8_t* __restrict__ qkT,
                            const float* __restrict__ ks_p, float* __restrict__ bmk) {
    __shared__ uint8_t sm[64 * 68];  // used by kT branch only
    __shared__ float red[4];
    const int t = threadIdx.x;
    float lmax = 0.0f;

    if (blockIdx.x < 64 * 64) {
        // ---- kernel^T branch: f32 [K][N] -> e4m3 [N][K] (K-permuted) ----
        const float inv = 1.0f / ks_p[0];
        const int bk = blockIdx.x & 63;   // K-tile index (64 tiles)
        const int bn = blockIdx.x >> 6;   // N-tile index (64 tiles)
        const int gk0 = bk * 64, gn0 = bn * 64;

        #pragma unroll
        for (int it = 0; it < 4; ++it) {
            int k  = it * 16 + (t >> 4);
            int n4 = (t & 15) * 4;
            float4 v = *(const float4*)(kin + (size_t)(gk0 + k) * N_DIM + gn0 + n4);
            lmax = fmaxf(lmax, fmaxf(fmaxf(fabsf(v.x), fabsf(v.y)),
                                     fmaxf(fabsf(v.z), fabsf(v.w))));
            *(uint32_t*)(sm + k * 68 + n4) = pk_fp8_x4(clip448(v.x * inv), clip448(v.y * inv),
                                                       clip448(v.z * inv), clip448(v.w * inv));
        }
        __syncthreads();
        #pragma unroll
        for (int it = 0; it < 4; ++it) {
            int n  = it * 16 + (t >> 4);
            int k4 = (t & 15) * 4;                  // 0..60, multiple of 4
            uint32_t w = (uint32_t)sm[(k4 + 0) * 68 + n]
                       | ((uint32_t)sm[(k4 + 1) * 68 + n] << 8)
                       | ((uint32_t)sm[(k4 + 2) * 68 + n] << 16)
                       | ((uint32_t)sm[(k4 + 3) * 68 + n] << 24);
            int kk = (gk0 + k4);
            size_t b = (size_t)(kk >> 7);           // 128-byte block
            int  kp  = kk & 127;
            int  c   = kp >> 5, g = (kp >> 3) & 3, j = kp & 7;   // j in {0,4}
            int  p   = g * 32 + c * 8 + j;
            *(uint32_t*)(qkT + (size_t)(gn0 + n) * K_DIM + b * 128 + p) = w;
        }
        #pragma unroll
        for (int off = 32; off; off >>= 1) lmax = fmaxf(lmax, __shfl_xor(lmax, off));
        if ((t & 63) == 0) red[t >> 6] = lmax;
        __syncthreads();
        if (t == 0)
            bmk[blockIdx.x] = fmaxf(fmaxf(red[0], red[1]), fmaxf(red[2], red[3]));
    } else {
        // ---- x branch: f32 [M][K] -> e4m3 [M][K] (K-permuted), grid-stride ----
        const float inv = 1.0f / xs_p[0];
        const int xbid = blockIdx.x - 64 * 64;      // 0..2047
        const int stride = 2048 * 256;
        const float4* xv = (const float4*)x;
        for (int u = xbid * 256 + t; u < n8; u += stride) {
            float4 v0 = xv[2 * u];
            float4 v1 = xv[2 * u + 1];
            lmax = fmaxf(lmax, fmaxf(fmaxf(fabsf(v0.x), fabsf(v0.y)),
                                     fmaxf(fabsf(v0.z), fabsf(v0.w))));
            lmax = fmaxf(lmax, fmaxf(fmaxf(fabsf(v1.x), fabsf(v1.y)),
                                     fmaxf(fabsf(v1.z), fabsf(v1.w))));
            uint32_t w0 = pk_fp8_x4(clip448(v0.x * inv), clip448(v0.y * inv),
                                    clip448(v0.z * inv), clip448(v0.w * inv));
            uint32_t w1 = pk_fp8_x4(clip448(v1.x * inv), clip448(v1.y * inv),
                                    clip448(v1.z * inv), clip448(v1.w * inv));
            // permuted 8B destination within 128B block
            size_t b  = (size_t)(u >> 4);   // 128-byte block
            int   u8  = u & 15;             // orig 8B unit = c*4 + g
            int   c   = u8 >> 2, g = u8 & 3;
            uint2* dst = (uint2*)(qx + b * 128 + (size_t)(g * 4 + c) * 8);
            *dst = make_uint2(w0, w1);
        }
        #pragma unroll
        for (int off = 32; off; off >>= 1) lmax = fmaxf(lmax, __shfl_xor(lmax, off));
        if ((t & 63) == 0) red[t >> 6] = lmax;
        __syncthreads();
        if (t == 0)
            bmx[xbid] = fmaxf(fmaxf(red[0], red[1]), fmaxf(red[2], red[3]));
    }
}

// ---------- MX-fp8 GEMM, 256x256 tile, 8-phase (r11 exactly — session best) ----------
// 8 waves (2M x 4N), per-wave 128x64 output = 8m x 4n fragments of 16x16.
// LDS: [dbuf][half] 16KB slots (128 KiB). 16B-unit XOR swizzle by (row&7)
// (pre-swizzled global source, linear gload_lds dest, swizzled ds_read;
// partner unit = p0^1 -> hi address = lo ^ 16).
// Per-lane LDS byte offsets precomputed before the K-loop; fragment concat
// via shufflevector. 8 phases / 2 K-tiles, 2 barriers per phase, counted
// lgkm inside the phase, vmcnt(4) at p4/p8. Prologue barrier after vmcnt(4).
// Measured (r11): 148.5 us, 1849 TF, MfmaUtil 38%. Ten structural variants
// (r6-r10, r12-r14) all regressed: wall = LDS-port + MFMA serialized is this
// structure's floor at HIP source level.

__device__ __forceinline__ i32x8 load_frag(const uint8_t* base, int off) {
    i32x4 lo = *(const i32x4*)(base + off);
    i32x4 hi = *(const i32x4*)(base + (off ^ 16));
    return __builtin_shufflevector(lo, hi, 0, 1, 2, 3, 4, 5, 6, 7);
}

#define SB __builtin_amdgcn_sched_barrier(0)
#define WAITL(N) do { asm volatile("s_waitcnt lgkmcnt(" #N ")" ::: "memory"); \
                      __builtin_amdgcn_sched_barrier(0); } while (0)
#define MM1(qq, nn, areg, breg)                                                 \
    acc[qq][nn] = __builtin_amdgcn_mfma_scale_f32_16x16x128_f8f6f4(             \
        areg, breg, acc[qq][nn], 0, 0, 0, UNIT_SCALE, 0, UNIT_SCALE)

__global__ __launch_bounds__(512, 2) void gemm_mx8(
        const uint8_t* __restrict__ A,   // [M][K] e4m3, K-permuted per 128B block
        const uint8_t* __restrict__ Bt,  // [N][K] e4m3, K-permuted per 128B block
        const float* __restrict__ bias,
        const float* __restrict__ sIn, const float* __restrict__ sK,
        float* __restrict__ C) {
    __shared__ uint8_t smA[2][2][16384];
    __shared__ uint8_t smB[2][2][16384];

    const int tid = threadIdx.x;
    const int lane = tid & 63, wid = tid >> 6;
    const int wm = wid >> 2, wn = wid & 3;
    const int r = lane & 15, g = lane >> 4;

    // XCD-bijective swizzle: 512 blocks, 512 % 8 == 0
    const int swz = (blockIdx.x & 7) * 64 + (blockIdx.x >> 3);
    const int mt = swz >> 4, nt = swz & 15;           // 32 x 16 tiles
    const int gRow0 = mt * 256, gCol0 = nt * 256;

    // staging geometry: idx in [0,1024); linear LDS dest idx*16.
    // row = idx>>3 (0..127), phys unit pu = idx&7 holds logical lu = pu ^ (row&7)
    const int idx0 = tid, idx1 = tid + 512;
    const int row0 = idx0 >> 3, row1 = idx1 >> 3;
    const size_t off0 = (size_t)row0 * K_DIM + (((idx0 & 7) ^ (row0 & 7)) * 16);
    const size_t off1 = (size_t)row1 * K_DIM + (((idx1 & 7) ^ (row1 & 7)) * 16);
    const int dst0 = idx0 * 16, dst1 = idx1 * 16;

    const uint8_t* Abase = A  + (size_t)gRow0 * K_DIM;
    const uint8_t* Bbase = Bt + (size_t)gCol0 * K_DIM;

#define STAGE_A(d, h, kt) do {                                                   \
    const uint8_t* s_ = Abase + (size_t)(h) * (128 * (size_t)K_DIM)              \
                              + (size_t)(kt) * 128;                              \
    gload_lds16(s_ + off0, &smA[d][h][dst0]);                                    \
    gload_lds16(s_ + off1, &smA[d][h][dst1]); } while (0)
#define STAGE_B(d, h, kt) do {                                                   \
    const uint8_t* s_ = Bbase + (size_t)(h) * (128 * (size_t)K_DIM)              \
                              + (size_t)(kt) * 128;                              \
    gload_lds16(s_ + off0, &smB[d][h][dst0]);                                    \
    gload_lds16(s_ + off1, &smB[d][h][dst1]); } while (0)

    f32x4 acc[8][4] = {};

    const int aHalf = wm;
    const int bHalf = wn >> 1;
    const int bRow  = (wn & 1) * 64;

    // precomputed within-operand byte offsets (lo unit) for all 12 fragments;
    // includes the half base so reads fold to (smbase + D*32768) + off
    int aoff[8], boff[4];
    #pragma unroll
    for (int m = 0; m < 8; ++m) {
        int lrow = m * 16 + r;
        aoff[m] = aHalf * 16384 + lrow * 128 + (((2 * g) ^ (lrow & 7)) * 16);
    }
    #pragma unroll
    for (int n = 0; n < 4; ++n) {
        int lrow = bRow + n * 16 + r;
        boff[n] = bHalf * 16384 + lrow * 128 + (((2 * g) ^ (lrow & 7)) * 16);
    }
    const uint8_t* smAb = &smA[0][0][0];
    const uint8_t* smBb = &smB[0][0][0];

    // prologue: B-K0, A-K0, B-K1 (6 half-units, 12 loads); keep B-K1 in flight
    STAGE_B(0, 0, 0); STAGE_B(0, 1, 0);
    STAGE_A(0, 0, 0); STAGE_A(0, 1, 0);
    STAGE_B(1, 0, 1); STAGE_B(1, 1, 1);
    asm volatile("s_waitcnt vmcnt(4)" ::: "memory");
    __builtin_amdgcn_s_barrier();                 // cross-wave visibility of kt0

    i32x8 bf0, bf1, bf2, bf3;

#define PHASE(D, Q, STAGE, VM) do {                                              \
    const uint8_t* As_ = smAb + (D) * 32768;                                     \
    const uint8_t* Bs_ = smBb + (D) * 32768;                                     \
    i32x8 a0, a1;                                                                \
    if ((Q) == 0) {                                                              \
        a0  = load_frag(As_, aoff[0]); SB;                                       \
        bf0 = load_frag(Bs_, boff[0]); SB;                                       \
        bf1 = load_frag(Bs_, boff[1]); SB;                                       \
        bf2 = load_frag(Bs_, boff[2]); SB;                                       \
        bf3 = load_frag(Bs_, boff[3]); SB;                                       \
        a1  = load_frag(As_, aoff[1]); SB;                                       \
    } else {                                                                     \
        a0 = load_frag(As_, aoff[2 * (Q) + 0]); SB;                              \
        a1 = load_frag(As_, aoff[2 * (Q) + 1]); SB;                              \
    }                                                                            \
    STAGE;                                                                       \
    __builtin_amdgcn_s_barrier();                                                \
    __builtin_amdgcn_s_setprio(1);                                               \
    if ((Q) == 0) {                                                              \
        WAITL(8); MM1(0, 0, a0, bf0);                                            \
        WAITL(6); MM1(0, 1, a0, bf1);                                            \
        WAITL(4); MM1(0, 2, a0, bf2);                                            \
        WAITL(2); MM1(0, 3, a0, bf3);                                            \
        WAITL(0); MM1(1, 0, a1, bf0); MM1(1, 1, a1, bf1);                        \
                  MM1(1, 2, a1, bf2); MM1(1, 3, a1, bf3);                        \
    } else {                                                                     \
        WAITL(2); MM1(2*(Q)+0, 0, a0, bf0); MM1(2*(Q)+0, 1, a0, bf1);            \
                  MM1(2*(Q)+0, 2, a0, bf2); MM1(2*(Q)+0, 3, a0, bf3);            \
        WAITL(0); MM1(2*(Q)+1, 0, a1, bf0); MM1(2*(Q)+1, 1, a1, bf1);            \
                  MM1(2*(Q)+1, 2, a1, bf2); MM1(2*(Q)+1, 3, a1, bf3);            \
    }                                                                            \
    __builtin_amdgcn_s_setprio(0);                                               \
    if (VM) asm volatile("s_waitcnt vmcnt(4)" ::: "memory");                     \
    __builtin_amdgcn_s_barrier();                                                \
} while (0)

    for (int i = 0; i < K_DIM / 256; ++i) {          // 16 iterations, 2 K-tiles each
        const int kt1  = 2 * i + 1;
        const int ktn0 = (2 * i + 2) & 31;           // wraps harmlessly on last iter
        const int ktn1 = (2 * i + 3) & 31;
        PHASE(0, 0, STAGE_A(1, 0, kt1),  0);
        PHASE(0, 1, STAGE_A(1, 1, kt1),  0);
        PHASE(0, 2, STAGE_B(0, 0, ktn0), 0);
        PHASE(0, 3, STAGE_B(0, 1, ktn0), 1);
        PHASE(1, 0, STAGE_A(0, 0, ktn0), 0);
        PHASE(1, 1, STAGE_A(0, 1, ktn0), 0);
        PHASE(1, 2, STAGE_B(1, 0, ktn1), 0);
        PHASE(1, 3, STAGE_B(1, 1, ktn1), 1);
    }

    const float s = sIn[0] * sK[0];
    #pragma unroll
    for (int n = 0; n < 4; ++n) {
        const int col = gCol0 + wn * 64 + n * 16 + r;
        const float bv = bias[col];
        #pragma unroll
        for (int m = 0; m < 8; ++m) {
            const int rw = gRow0 + wm * 128 + m * 16 + g * 4;
            #pragma unroll
            for (int reg = 0; reg < 4; ++reg)
                C[(size_t)(rw + reg) * N_DIM + col] = acc[m][n][reg] * s + bv;
        }
    }
#undef PHASE
#undef STAGE_A
#undef STAGE_B
}

// ---------- reduce block maxes + rolling-amax state update ----------
__global__ void state_kernel(const float* __restrict__ bmx, int nx,
                             const float* __restrict__ bmk, int nk,
                             const float* __restrict__ inHist,
                             const float* __restrict__ kHist,
                             float* __restrict__ tail) {
    __shared__ float red[8];
    const int t = threadIdx.x;
    float mx = 0.0f, mk = 0.0f;
    for (int i = t; i < nx; i += 256) mx = fmaxf(mx, bmx[i]);
    for (int i = t; i < nk; i += 256) mk = fmaxf(mk, bmk[i]);
    #pragma unroll
    for (int off = 32; off; off >>= 1) {
        mx = fmaxf(mx, __shfl_xor(mx, off));
        mk = fmaxf(mk, __shfl_xor(mk, off));
    }
    if ((t & 63) == 0) { red[t >> 6] = mx; red[4 + (t >> 6)] = mk; }
    __syncthreads();
    if (t == 0) {
        float amax_x = fmaxf(fmaxf(red[0], red[1]), fmaxf(red[2], red[3]));
        float amax_k = fmaxf(fmaxf(red[4], red[5]), fmaxf(red[6], red[7]));
        #pragma unroll
        for (int which = 0; which < 2; ++which) {
            const float* h = which ? kHist : inHist;
            float ac = which ? amax_k : amax_x;
            float m = fmaxf(0.0009765625f, ac);   // 2^-10
            tail[2 + which * 16 + 0] = ac;
            for (int i = 1; i < 16; ++i) {
                float v = h[i - 1];
                tail[2 + which * 16 + i] = v;
                m = fmaxf(m, v);
            }
            tail[which] = 1.1f * m / 448.0f;
        }
    }
}

extern "C" void kernel_launch(void* const* d_in, const int* in_sizes, int n_in,
                              void* d_out, int out_size, void* d_ws, size_t ws_size,
                              hipStream_t stream) {
    const float* x        = (const float*)d_in[0];
    const float* kern     = (const float*)d_in[1];
    const float* bias     = (const float*)d_in[2];
    const float* in_scale = (const float*)d_in[3];
    const float* k_scale  = (const float*)d_in[4];
    const float* in_hist  = (const float*)d_in[7];
    const float* k_hist   = (const float*)d_in[8];

    const int NBX = 2048;              // quant_x blocks
    const int NBK = 64 * 64;           // quant_kT blocks
    const size_t qx_bytes  = (size_t)M_DIM * K_DIM;       // 32 MiB
    const size_t qkT_bytes = (size_t)K_DIM * N_DIM;       // 16 MiB
    const size_t need = qx_bytes + qkT_bytes + (NBX + NBK) * sizeof(float);
    if (ws_size < need) return;  // fail visibly, no corruption

    uint8_t* qx  = (uint8_t*)d_ws;
    uint8_t* qkT = qx + qx_bytes;
    float*   bmx = (float*)(qkT + qkT_bytes);
    float*   bmk = bmx + NBX;
    float*   out = (float*)d_out;

    quant_fused<<<NBK + NBX, 256, 0, stream>>>(x, qx, in_scale, bmx,
                                               (int)((size_t)M_DIM * K_DIM / 8),
                                               kern, qkT, k_scale, bmk);
    gemm_mx8<<<(M_DIM / 256) * (N_DIM / 256), 512, 0, stream>>>(qx, qkT, bias,
                                                                in_scale, k_scale, out);
    state_kernel<<<1, 256, 0, stream>>>(bmx, NBX, bmk, NBK, in_hist, k_hist,
                                        out + (size_t)M_DIM * N_DIM);
}